// Round 4
// baseline (267.939 us; speedup 1.0000x reference)
//
#include <hip/hip_runtime.h>

// CrossAttention: b=4, n=2048, m=1024, qd=1024, cd=768, heads=8, dh=64, inner=512
// Round 4:
//   prep_cast   : x,ctx -> bf16
//   prep_weights: 4 transposes fused (SCALE*log2e folded into Wq)
//   proj_gemm   : Q + KV GEMM fused, m97-style 128x128 tiles (512 blocks)
//   attn_kernel : 16 q/wave, 1024 blocks (4/CU, 16 waves/CU for phase overlap),
//                 l-sum via ones-MFMA (no VALU adds, no epilogue shuffles)
//   gemm_out    : 128x128 f32+bias (512 blocks)

typedef __bf16 bf16x8_t __attribute__((ext_vector_type(8)));
typedef __bf16 bf16x4_t __attribute__((ext_vector_type(4)));
typedef float  f32x4_t  __attribute__((ext_vector_type(4)));

#define GLOAD_LDS16(gptr, lptr)                                                  \
  __builtin_amdgcn_global_load_lds(                                              \
      (const __attribute__((address_space(1))) void*)(gptr),                     \
      (__attribute__((address_space(3))) void*)(lptr), 16, 0, 0)

// ---------------- fused cast fp32 -> bf16 ----------------
__global__ __launch_bounds__(256) void prep_cast(const float* __restrict__ x,
                                                 __bf16* __restrict__ xb,
                                                 const float* __restrict__ ctx,
                                                 __bf16* __restrict__ cb) {
  const int NX = 8192 * 1024 / 8;
  int g = blockIdx.x * 256 + threadIdx.x;
  const float* src;
  __bf16* dst;
  if (g < NX) { src = x; dst = xb; }
  else        { src = ctx; dst = cb; g -= NX; }
  size_t i = (size_t)g * 8;
  float4 a = *(const float4*)(src + i);
  float4 b = *(const float4*)(src + i + 4);
  bf16x8_t v;
  v[0] = (__bf16)a.x; v[1] = (__bf16)a.y; v[2] = (__bf16)a.z; v[3] = (__bf16)a.w;
  v[4] = (__bf16)b.x; v[5] = (__bf16)b.y; v[6] = (__bf16)b.z; v[7] = (__bf16)b.w;
  *(bf16x8_t*)(dst + i) = v;
}

// ---------------- fused weight transposes ----------------
__global__ __launch_bounds__(256) void prep_weights(const float* __restrict__ Wq,
                                                    const float* __restrict__ Wk,
                                                    const float* __restrict__ Wv,
                                                    const float* __restrict__ Wout,
                                                    __bf16* __restrict__ WqT,
                                                    __bf16* __restrict__ WkvT,
                                                    __bf16* __restrict__ WoutT,
                                                    float qscale) {
  __shared__ float tile[32][33];
  int bid = blockIdx.x;
  const float* src; __bf16* dst; int R, C; float scale; int t;
  if (bid < 512)       { src = Wq;   dst = WqT;   R = 1024; C = 512;  scale = qscale; t = bid; }
  else if (bid < 896)  { src = Wk;   dst = WkvT;  R = 768;  C = 512;  scale = 1.f; t = bid - 512; }
  else if (bid < 1280) { src = Wv;   dst = WkvT + (size_t)512 * 768; R = 768; C = 512; scale = 1.f; t = bid - 896; }
  else                 { src = Wout; dst = WoutT; R = 512;  C = 1024; scale = 1.f; t = bid - 1280; }
  int tilesX = C >> 5;
  int c0 = (t % tilesX) * 32, r0 = (t / tilesX) * 32;
  int tx = threadIdx.x & 31, ty = threadIdx.x >> 5;
#pragma unroll
  for (int i = 0; i < 32; i += 8)
    tile[ty + i][tx] = src[(size_t)(r0 + ty + i) * C + (c0 + tx)];
  __syncthreads();
#pragma unroll
  for (int i = 0; i < 32; i += 8)
    dst[(size_t)(c0 + ty + i) * R + (r0 + tx)] = (__bf16)(tile[tx][ty + i] * scale);
}

// ------------- fused Q + KV projection GEMM, 128x128 tiles (m97 structure) -------------
// blocks 0-255 : Qs[8192x512] = xb @ WqT^T (K=1024), bm=(idx>>2)*128, bn=(idx&3)*128
// blocks 256-511: Ks/Vt = cb @ WkvT^T (K=768), bm=(idx>>3)*128, bn=(idx&7)*128;
//                cols>=512 are V -> written transposed to Vt[b][dg][m]
__global__ __launch_bounds__(256) void proj_gemm(const __bf16* __restrict__ xb,
                                                 const __bf16* __restrict__ WqT,
                                                 __bf16* __restrict__ Qs,
                                                 const __bf16* __restrict__ cb,
                                                 const __bf16* __restrict__ WkvT,
                                                 __bf16* __restrict__ Ks,
                                                 __bf16* __restrict__ Vt) {
  __shared__ __align__(16) __bf16 As[128 * 32];
  __shared__ __align__(16) __bf16 Bs[128 * 32];
  const int bid = blockIdx.x;
  const bool isQ = bid < 256;
  const int idx = isQ ? bid : bid - 256;
  const __bf16 *A, *B;
  int K, bm, bn;
  if (isQ) { A = xb; B = WqT;  K = 1024; bm = (idx >> 2) * 128; bn = (idx & 3) * 128; }
  else     { A = cb; B = WkvT; K = 768;  bm = (idx >> 3) * 128; bn = (idx & 7) * 128; }

  const int tid  = threadIdx.x;
  const int wave = tid >> 6;
  const int lane = tid & 63;
  const int quad = lane >> 4;
  const int l16  = lane & 15;
  const int wm = (wave >> 1) * 64;
  const int wn = (wave & 1) * 64;
  const int sRow = tid >> 2;
  const int sCol = (tid & 3) * 8;

  f32x4_t acc[4][4] = {};

  for (int kk = 0; kk < K; kk += 32) {
    __syncthreads();
#pragma unroll
    for (int it = 0; it < 2; ++it) {
      GLOAD_LDS16(A + (size_t)(bm + it * 64 + sRow) * K + kk + sCol, As + it * 2048 + wave * 512);
      GLOAD_LDS16(B + (size_t)(bn + it * 64 + sRow) * K + kk + sCol, Bs + it * 2048 + wave * 512);
    }
    __syncthreads();
    bf16x8_t af[4], bf[4];
#pragma unroll
    for (int i = 0; i < 4; ++i) {
      af[i] = *(const bf16x8_t*)(As + (wm + i * 16 + l16) * 32 + quad * 8);
      bf[i] = *(const bf16x8_t*)(Bs + (wn + i * 16 + l16) * 32 + quad * 8);
    }
#pragma unroll
    for (int i = 0; i < 4; ++i)
#pragma unroll
      for (int j = 0; j < 4; ++j)
        acc[i][j] = __builtin_amdgcn_mfma_f32_16x16x32_bf16(af[i], bf[j], acc[i][j], 0, 0, 0);
  }

#pragma unroll
  for (int i = 0; i < 4; ++i) {
    int row = bm + wm + i * 16 + quad * 4;
#pragma unroll
    for (int j = 0; j < 4; ++j) {
      int col = bn + wn + j * 16 + l16;
      f32x4_t v = acc[i][j];
      if (isQ) {
#pragma unroll
        for (int r = 0; r < 4; ++r) Qs[(size_t)(row + r) * 512 + col] = (__bf16)v[r];
      } else if (col < 512) {
#pragma unroll
        for (int r = 0; r < 4; ++r) Ks[(size_t)(row + r) * 512 + col] = (__bf16)v[r];
      } else {
        int dg = col - 512;
        int bb = row >> 10, m0 = row & 1023;
        bf16x4_t pk;
        pk[0] = (__bf16)v[0]; pk[1] = (__bf16)v[1];
        pk[2] = (__bf16)v[2]; pk[3] = (__bf16)v[3];
        *(bf16x4_t*)(Vt + ((size_t)bb * 512 + dg) * 1024 + m0) = pk;
      }
    }
  }
}

// ------------- out projection GEMM, 128x128 tiles, f32 + bias -------------
__global__ __launch_bounds__(256) void gemm_out(const __bf16* __restrict__ A,
                                                const __bf16* __restrict__ B,
                                                float* __restrict__ C,
                                                const float* __restrict__ bias) {
  __shared__ __align__(16) __bf16 As[128 * 32];
  __shared__ __align__(16) __bf16 Bs[128 * 32];
  const int K = 512, N = 1024;
  const int tid  = threadIdx.x;
  const int wave = tid >> 6;
  const int lane = tid & 63;
  const int quad = lane >> 4;
  const int l16  = lane & 15;
  const int wm = (wave >> 1) * 64;
  const int wn = (wave & 1) * 64;
  const int bm = blockIdx.x * 128;
  const int bn = blockIdx.y * 128;
  const int sRow = tid >> 2;
  const int sCol = (tid & 3) * 8;

  f32x4_t acc[4][4] = {};

  for (int kk = 0; kk < K; kk += 32) {
    __syncthreads();
#pragma unroll
    for (int it = 0; it < 2; ++it) {
      GLOAD_LDS16(A + (size_t)(bm + it * 64 + sRow) * K + kk + sCol, As + it * 2048 + wave * 512);
      GLOAD_LDS16(B + (size_t)(bn + it * 64 + sRow) * K + kk + sCol, Bs + it * 2048 + wave * 512);
    }
    __syncthreads();
    bf16x8_t af[4], bf[4];
#pragma unroll
    for (int i = 0; i < 4; ++i) {
      af[i] = *(const bf16x8_t*)(As + (wm + i * 16 + l16) * 32 + quad * 8);
      bf[i] = *(const bf16x8_t*)(Bs + (wn + i * 16 + l16) * 32 + quad * 8);
    }
#pragma unroll
    for (int i = 0; i < 4; ++i)
#pragma unroll
      for (int j = 0; j < 4; ++j)
        acc[i][j] = __builtin_amdgcn_mfma_f32_16x16x32_bf16(af[i], bf[j], acc[i][j], 0, 0, 0);
  }

#pragma unroll
  for (int i = 0; i < 4; ++i) {
    int row = bm + wm + i * 16 + quad * 4;
#pragma unroll
    for (int j = 0; j < 4; ++j) {
      int col = bn + wn + j * 16 + l16;
      float bb = bias[col];
      f32x4_t v = acc[i][j];
#pragma unroll
      for (int r = 0; r < 4; ++r) C[(size_t)(row + r) * N + col] = v[r] + bb;
    }
  }
}

// ------------- flash attention: 16 q/wave, high-occupancy -------------
// grid (32 hb, 32 qt) = 1024 blocks -> 4 blocks/CU, 16 waves/CU.
// Per wave-iter: 8 QK MFMA, 16 exp2, P->LDS roundtrip, 2 ones-MFMA (l), 8 PV MFMA.
// l lands in C-layout on exactly the lanes holding oacc rows -> no shuffles.
__global__ __launch_bounds__(256, 4) void attn_kernel(const __bf16* __restrict__ Q,
                                                      const __bf16* __restrict__ K,
                                                      const __bf16* __restrict__ Vt,
                                                      __bf16* __restrict__ O) {
  const int hb = blockIdx.x, h = hb >> 2, b = hb & 3;
  const int qt = blockIdx.y;
  const int tid = threadIdx.x, wave = tid >> 6, lane = tid & 63;
  const int quad = lane >> 4, l16 = lane & 15;

  __shared__ __align__(16) __bf16 Ps[4][16 * 72];
  __bf16* myP = Ps[wave];

  const int q0 = qt * 64 + wave * 16;

  bf16x8_t qa[2];
#pragma unroll
  for (int hf = 0; hf < 2; ++hf)
    qa[hf] = *(const bf16x8_t*)(Q + (size_t)(b * 2048 + q0 + l16) * 512 +
                                h * 64 + hf * 32 + quad * 8);

  const __bf16* Kb = K + (size_t)b * 1024 * 512 + h * 64;
  const __bf16* Vb = Vt + (size_t)b * 512 * 1024 + (size_t)h * 64 * 1024;

  bf16x8_t ones;
#pragma unroll
  for (int j = 0; j < 8; ++j) ones[j] = (__bf16)1.0f;

  f32x4_t oacc[4] = {};
  f32x4_t lacc = {};

  for (int mm = 0; mm < 1024; mm += 64) {
    // K fragments for this tile
    bf16x8_t kf[4][2];
#pragma unroll
    for (int nt = 0; nt < 4; ++nt)
#pragma unroll
      for (int hf = 0; hf < 2; ++hf)
        kf[nt][hf] = *(const bf16x8_t*)(Kb + (size_t)(mm + nt * 16 + l16) * 512 +
                                        hf * 32 + quad * 8);

    // S = Q K^T (16 q x 64 keys)
    f32x4_t s[4];
#pragma unroll
    for (int nt = 0; nt < 4; ++nt) {
      f32x4_t z = {};
      z = __builtin_amdgcn_mfma_f32_16x16x32_bf16(qa[0], kf[nt][0], z, 0, 0, 0);
      s[nt] = __builtin_amdgcn_mfma_f32_16x16x32_bf16(qa[1], kf[nt][1], z, 0, 0, 0);
    }

    // V frags: issue now, consumed after the exp/LDS phase (latency hidden)
    bf16x8_t vf[4][2];
#pragma unroll
    for (int dt = 0; dt < 4; ++dt)
#pragma unroll
      for (int hf = 0; hf < 2; ++hf)
        vf[dt][hf] = *(const bf16x8_t*)(Vb + (size_t)(dt * 16 + l16) * 1024 +
                                        mm + hf * 32 + quad * 8);

    // p = exp2(s) -> LDS (A-layout rows)
#pragma unroll
    for (int nt = 0; nt < 4; ++nt)
#pragma unroll
      for (int r = 0; r < 4; ++r)
        myP[(quad * 4 + r) * 72 + nt * 16 + l16] = (__bf16)__builtin_exp2f(s[nt][r]);

    bf16x8_t pa[2];
#pragma unroll
    for (int hf = 0; hf < 2; ++hf)
      pa[hf] = *(const bf16x8_t*)(myP + l16 * 72 + hf * 32 + quad * 8);

    // row-sum l via ones-MFMA (C layout: same lanes/regs as oacc rows)
    lacc = __builtin_amdgcn_mfma_f32_16x16x32_bf16(pa[0], ones, lacc, 0, 0, 0);
    lacc = __builtin_amdgcn_mfma_f32_16x16x32_bf16(pa[1], ones, lacc, 0, 0, 0);

#pragma unroll
    for (int dt = 0; dt < 4; ++dt) {
      oacc[dt] = __builtin_amdgcn_mfma_f32_16x16x32_bf16(pa[0], vf[dt][0], oacc[dt], 0, 0, 0);
      oacc[dt] = __builtin_amdgcn_mfma_f32_16x16x32_bf16(pa[1], vf[dt][1], oacc[dt], 0, 0, 0);
    }
  }

  // epilogue: lane (l16,quad) reg r holds both l and oacc for query quad*4+r
#pragma unroll
  for (int r = 0; r < 4; ++r) {
    float inv = 1.f / lacc[r];
    size_t orow = (size_t)(b * 2048 + q0 + quad * 4 + r) * 512 + h * 64;
#pragma unroll
    for (int dt = 0; dt < 4; ++dt)
      O[orow + dt * 16 + l16] = (__bf16)(oacc[dt][r] * inv);
  }
}

// ---------------- launch ----------------
extern "C" void kernel_launch(void* const* d_in, const int* in_sizes, int n_in,
                              void* d_out, int out_size, void* d_ws, size_t ws_size,
                              hipStream_t stream) {
  const float* x    = (const float*)d_in[0];
  const float* ctx  = (const float*)d_in[1];
  const float* Wq   = (const float*)d_in[2];
  const float* Wk   = (const float*)d_in[3];
  const float* Wv   = (const float*)d_in[4];
  const float* Wout = (const float*)d_in[5];
  const float* bout = (const float*)d_in[6];
  float* out = (float*)d_out;

  char* ws = (char*)d_ws;
  size_t off = 0;
  auto alloc = [&](size_t bytes) {
    void* p = ws + off;
    off = (off + bytes + 255) & ~(size_t)255;
    return p;
  };
  __bf16* xb    = (__bf16*)alloc((size_t)8192 * 1024 * 2);
  __bf16* cb    = (__bf16*)alloc((size_t)4096 * 768 * 2);
  __bf16* WqT   = (__bf16*)alloc((size_t)512 * 1024 * 2);
  __bf16* WkvT  = (__bf16*)alloc((size_t)1024 * 768 * 2);
  __bf16* WoutT = (__bf16*)alloc((size_t)1024 * 512 * 2);
  __bf16* Qs    = (__bf16*)alloc((size_t)8192 * 512 * 2);
  __bf16* Ks    = (__bf16*)alloc((size_t)4096 * 512 * 2);
  __bf16* Vt    = (__bf16*)alloc((size_t)4 * 512 * 1024 * 2);
  __bf16* Os    = (__bf16*)alloc((size_t)8192 * 512 * 2);

  const float QSCALE = 0.125f * 1.4426950408889634f;  // dh^-0.5 * log2(e)

  prep_cast<<<5632, 256, 0, stream>>>(x, xb, ctx, cb);
  prep_weights<<<1792, 256, 0, stream>>>(Wq, Wk, Wv, Wout, WqT, WkvT, WoutT, QSCALE);
  proj_gemm<<<512, 256, 0, stream>>>(xb, WqT, Qs, cb, WkvT, Ks, Vt);
  attn_kernel<<<dim3(32, 32), 256, 0, stream>>>(Qs, Ks, Vt, Os);
  gemm_out<<<dim3(64, 8), 256, 0, stream>>>(Os, WoutT, out, bout);
}

// Round 6
// 185.043 us; speedup vs baseline: 1.4480x; 1.4480x over previous
//
#include <hip/hip_runtime.h>

// CrossAttention: b=4, n=2048, m=1024, qd=1024, cd=768, heads=8, dh=64, inner=512
// Round 6 (round-5 fix: removed forward-use of b_row helper):
//   attn: 32 q/wave, grid (32 hb, 16 qt). K/V tiles staged ONCE per block per
//   iter via global_load_lds with XOR swizzle (conflict-free b128 frag reads).
//   l-sum via ones-MFMA. Other kernels = m97-style 128x128 GEMMs.

typedef __bf16 bf16x8_t __attribute__((ext_vector_type(8)));
typedef __bf16 bf16x4_t __attribute__((ext_vector_type(4)));
typedef float  f32x4_t  __attribute__((ext_vector_type(4)));

#define GLOAD_LDS16(gptr, lptr)                                                  \
  __builtin_amdgcn_global_load_lds(                                              \
      (const __attribute__((address_space(1))) void*)(gptr),                     \
      (__attribute__((address_space(3))) void*)(lptr), 16, 0, 0)

// ---------------- fused cast fp32 -> bf16 ----------------
__global__ __launch_bounds__(256) void prep_cast(const float* __restrict__ x,
                                                 __bf16* __restrict__ xb,
                                                 const float* __restrict__ ctx,
                                                 __bf16* __restrict__ cb) {
  const int NX = 8192 * 1024 / 8;
  int g = blockIdx.x * 256 + threadIdx.x;
  const float* src;
  __bf16* dst;
  if (g < NX) { src = x; dst = xb; }
  else        { src = ctx; dst = cb; g -= NX; }
  size_t i = (size_t)g * 8;
  float4 a = *(const float4*)(src + i);
  float4 b = *(const float4*)(src + i + 4);
  bf16x8_t v;
  v[0] = (__bf16)a.x; v[1] = (__bf16)a.y; v[2] = (__bf16)a.z; v[3] = (__bf16)a.w;
  v[4] = (__bf16)b.x; v[5] = (__bf16)b.y; v[6] = (__bf16)b.z; v[7] = (__bf16)b.w;
  *(bf16x8_t*)(dst + i) = v;
}

// ---------------- fused weight transposes ----------------
__global__ __launch_bounds__(256) void prep_weights(const float* __restrict__ Wq,
                                                    const float* __restrict__ Wk,
                                                    const float* __restrict__ Wv,
                                                    const float* __restrict__ Wout,
                                                    __bf16* __restrict__ WqT,
                                                    __bf16* __restrict__ WkvT,
                                                    __bf16* __restrict__ WoutT,
                                                    float qscale) {
  __shared__ float tile[32][33];
  int bid = blockIdx.x;
  const float* src; __bf16* dst; int R, C; float scale; int t;
  if (bid < 512)       { src = Wq;   dst = WqT;   R = 1024; C = 512;  scale = qscale; t = bid; }
  else if (bid < 896)  { src = Wk;   dst = WkvT;  R = 768;  C = 512;  scale = 1.f; t = bid - 512; }
  else if (bid < 1280) { src = Wv;   dst = WkvT + (size_t)512 * 768; R = 768; C = 512; scale = 1.f; t = bid - 896; }
  else                 { src = Wout; dst = WoutT; R = 512;  C = 1024; scale = 1.f; t = bid - 1280; }
  int tilesX = C >> 5;
  int c0 = (t % tilesX) * 32, r0 = (t / tilesX) * 32;
  int tx = threadIdx.x & 31, ty = threadIdx.x >> 5;
#pragma unroll
  for (int i = 0; i < 32; i += 8)
    tile[ty + i][tx] = src[(size_t)(r0 + ty + i) * C + (c0 + tx)];
  __syncthreads();
#pragma unroll
  for (int i = 0; i < 32; i += 8)
    dst[(size_t)(c0 + ty + i) * R + (r0 + tx)] = (__bf16)(tile[tx][ty + i] * scale);
}

// ------------- fused Q + KV projection GEMM, 128x128 tiles -------------
__global__ __launch_bounds__(256) void proj_gemm(const __bf16* __restrict__ xb,
                                                 const __bf16* __restrict__ WqT,
                                                 __bf16* __restrict__ Qs,
                                                 const __bf16* __restrict__ cb,
                                                 const __bf16* __restrict__ WkvT,
                                                 __bf16* __restrict__ Ks,
                                                 __bf16* __restrict__ Vt) {
  __shared__ __align__(16) __bf16 As[128 * 32];
  __shared__ __align__(16) __bf16 Bs[128 * 32];
  const int bid = blockIdx.x;
  const bool isQ = bid < 256;
  const int idx = isQ ? bid : bid - 256;
  const __bf16 *A, *B;
  int K, bm, bn;
  if (isQ) { A = xb; B = WqT;  K = 1024; bm = (idx >> 2) * 128; bn = (idx & 3) * 128; }
  else     { A = cb; B = WkvT; K = 768;  bm = (idx >> 3) * 128; bn = (idx & 7) * 128; }

  const int tid  = threadIdx.x;
  const int wave = tid >> 6;
  const int lane = tid & 63;
  const int quad = lane >> 4;
  const int l16  = lane & 15;
  const int wm = (wave >> 1) * 64;
  const int wn = (wave & 1) * 64;
  const int sRow = tid >> 2;
  const int sCol = (tid & 3) * 8;

  f32x4_t acc[4][4] = {};

  for (int kk = 0; kk < K; kk += 32) {
    __syncthreads();
#pragma unroll
    for (int it = 0; it < 2; ++it) {
      GLOAD_LDS16(A + (size_t)(bm + it * 64 + sRow) * K + kk + sCol, As + it * 2048 + wave * 512);
      GLOAD_LDS16(B + (size_t)(bn + it * 64 + sRow) * K + kk + sCol, Bs + it * 2048 + wave * 512);
    }
    __syncthreads();
    bf16x8_t af[4], bf[4];
#pragma unroll
    for (int i = 0; i < 4; ++i) {
      af[i] = *(const bf16x8_t*)(As + (wm + i * 16 + l16) * 32 + quad * 8);
      bf[i] = *(const bf16x8_t*)(Bs + (wn + i * 16 + l16) * 32 + quad * 8);
    }
#pragma unroll
    for (int i = 0; i < 4; ++i)
#pragma unroll
      for (int j = 0; j < 4; ++j)
        acc[i][j] = __builtin_amdgcn_mfma_f32_16x16x32_bf16(af[i], bf[j], acc[i][j], 0, 0, 0);
  }

#pragma unroll
  for (int i = 0; i < 4; ++i) {
    int row = bm + wm + i * 16 + quad * 4;
#pragma unroll
    for (int j = 0; j < 4; ++j) {
      int col = bn + wn + j * 16 + l16;
      f32x4_t v = acc[i][j];
      if (isQ) {
#pragma unroll
        for (int r = 0; r < 4; ++r) Qs[(size_t)(row + r) * 512 + col] = (__bf16)v[r];
      } else if (col < 512) {
#pragma unroll
        for (int r = 0; r < 4; ++r) Ks[(size_t)(row + r) * 512 + col] = (__bf16)v[r];
      } else {
        int dg = col - 512;
        int bb = row >> 10, m0 = row & 1023;
        bf16x4_t pk;
        pk[0] = (__bf16)v[0]; pk[1] = (__bf16)v[1];
        pk[2] = (__bf16)v[2]; pk[3] = (__bf16)v[3];
        *(bf16x4_t*)(Vt + ((size_t)bb * 512 + dg) * 1024 + m0) = pk;
      }
    }
  }
}

// ------------- out projection GEMM, 128x128 tiles, f32 + bias -------------
__global__ __launch_bounds__(256) void gemm_out(const __bf16* __restrict__ A,
                                                const __bf16* __restrict__ B,
                                                float* __restrict__ C,
                                                const float* __restrict__ bias) {
  __shared__ __align__(16) __bf16 As[128 * 32];
  __shared__ __align__(16) __bf16 Bs[128 * 32];
  const int K = 512, N = 1024;
  const int tid  = threadIdx.x;
  const int wave = tid >> 6;
  const int lane = tid & 63;
  const int quad = lane >> 4;
  const int l16  = lane & 15;
  const int wm = (wave >> 1) * 64;
  const int wn = (wave & 1) * 64;
  const int bm = blockIdx.x * 128;
  const int bn = blockIdx.y * 128;
  const int sRow = tid >> 2;
  const int sCol = (tid & 3) * 8;

  f32x4_t acc[4][4] = {};

  for (int kk = 0; kk < K; kk += 32) {
    __syncthreads();
#pragma unroll
    for (int it = 0; it < 2; ++it) {
      GLOAD_LDS16(A + (size_t)(bm + it * 64 + sRow) * K + kk + sCol, As + it * 2048 + wave * 512);
      GLOAD_LDS16(B + (size_t)(bn + it * 64 + sRow) * K + kk + sCol, Bs + it * 2048 + wave * 512);
    }
    __syncthreads();
    bf16x8_t af[4], bf[4];
#pragma unroll
    for (int i = 0; i < 4; ++i) {
      af[i] = *(const bf16x8_t*)(As + (wm + i * 16 + l16) * 32 + quad * 8);
      bf[i] = *(const bf16x8_t*)(Bs + (wn + i * 16 + l16) * 32 + quad * 8);
    }
#pragma unroll
    for (int i = 0; i < 4; ++i)
#pragma unroll
      for (int j = 0; j < 4; ++j)
        acc[i][j] = __builtin_amdgcn_mfma_f32_16x16x32_bf16(af[i], bf[j], acc[i][j], 0, 0, 0);
  }

#pragma unroll
  for (int i = 0; i < 4; ++i) {
    int row = bm + wm + i * 16 + quad * 4;
#pragma unroll
    for (int j = 0; j < 4; ++j) {
      int col = bn + wn + j * 16 + l16;
      float bb = bias[col];
      f32x4_t v = acc[i][j];
#pragma unroll
      for (int r = 0; r < 4; ++r) C[(size_t)(row + r) * N + col] = v[r] + bb;
    }
  }
}

// ------------- flash attention: LDS-staged K/V with XOR swizzle -------------
// grid (32 hb, 16 qt) = 512 blocks, 4 waves, 32 q/wave (128 q/block).
// K tile (64 keys x 64 d) and V tile (64 d x 64 keys, from Vt) staged once per
// block per iter via global_load_lds; chunk c of row r stored at slot c^(r&7)
// so fragment ds_read_b128 hits all 32 banks (2 lanes/bank = free).
__global__ void attn_kernel(const __bf16* __restrict__ Q,
                            const __bf16* __restrict__ K,
                            const __bf16* __restrict__ Vt,
                            __bf16* __restrict__ O) {
  const int hb = blockIdx.x, h = hb >> 2, b = hb & 3;
  const int qt = blockIdx.y;
  const int tid = threadIdx.x, wave = tid >> 6, lane = tid & 63;
  const int quad = lane >> 4, l16 = lane & 15;

  __shared__ __align__(16) __bf16 Kt[64 * 64];
  __shared__ __align__(16) __bf16 Vs[64 * 64];
  __shared__ __align__(16) __bf16 Ps[4][32 * 72];
  __bf16* myP = Ps[wave];

  const int q0 = qt * 128 + wave * 32;

  bf16x8_t qa[2][2];
#pragma unroll
  for (int t = 0; t < 2; ++t)
#pragma unroll
    for (int hf = 0; hf < 2; ++hf)
      qa[t][hf] = *(const bf16x8_t*)(Q + (size_t)(b * 2048 + q0 + t * 16 + l16) * 512 +
                                     h * 64 + hf * 32 + quad * 8);

  const __bf16* Kb = K + (size_t)b * 1024 * 512 + h * 64;
  const __bf16* Vb = Vt + (size_t)b * 512 * 1024 + (size_t)h * 64 * 1024;

  bf16x8_t ones;
#pragma unroll
  for (int j = 0; j < 8; ++j) ones[j] = (__bf16)1.0f;

  f32x4_t oacc[2][4] = {};
  f32x4_t lacc[2] = {};

  // staging: lane -> 16B slot; local row = base + lane/8, slot p = lane%8.
  // slot p receives global chunk c = p ^ ((base+lane/8)&7); since base is a
  // multiple of 8, (base+lane/8)&7 == lane>>3.
  const int sr = lane >> 3;
  const int sc = (lane & 7) ^ sr;        // global chunk to fetch (8 bf16)
  const int swz = l16 & 7;               // read-side swizzle key (row&7)

  for (int mm = 0; mm < 1024; mm += 64) {
    __syncthreads();
#pragma unroll
    for (int t = 0; t < 2; ++t) {
      const int rl = wave * 16 + t * 8;  // tile-local base row (mult of 8)
      GLOAD_LDS16(Kb + (size_t)(mm + rl + sr) * 512 + sc * 8, Kt + rl * 64);
      GLOAD_LDS16(Vb + (size_t)(rl + sr) * 1024 + mm + sc * 8, Vs + rl * 64);
    }
    __syncthreads();

    // K B-frags: row = nt*16+l16 (key), chunk hf*4+quad, swizzled by row&7
    bf16x8_t kf[4][2];
#pragma unroll
    for (int nt = 0; nt < 4; ++nt)
#pragma unroll
      for (int hf = 0; hf < 2; ++hf)
        kf[nt][hf] = *(const bf16x8_t*)(Kt + (nt * 16 + l16) * 64 +
                                        (((hf << 2) | quad) ^ swz) * 8);

    // S = Q K^T
    f32x4_t s[2][4];
#pragma unroll
    for (int t = 0; t < 2; ++t)
#pragma unroll
      for (int nt = 0; nt < 4; ++nt) {
        f32x4_t z = {};
        z = __builtin_amdgcn_mfma_f32_16x16x32_bf16(qa[t][0], kf[nt][0], z, 0, 0, 0);
        s[t][nt] = __builtin_amdgcn_mfma_f32_16x16x32_bf16(qa[t][1], kf[nt][1], z, 0, 0, 0);
      }

    // p = exp2(s) -> per-wave LDS (A-layout rows)
#pragma unroll
    for (int t = 0; t < 2; ++t)
#pragma unroll
      for (int nt = 0; nt < 4; ++nt)
#pragma unroll
        for (int r = 0; r < 4; ++r)
          myP[(t * 16 + quad * 4 + r) * 72 + nt * 16 + l16] =
              (__bf16)__builtin_exp2f(s[t][nt][r]);

    bf16x8_t pa[2][2];
#pragma unroll
    for (int t = 0; t < 2; ++t)
#pragma unroll
      for (int hf = 0; hf < 2; ++hf)
        pa[t][hf] = *(const bf16x8_t*)(myP + (t * 16 + l16) * 72 + hf * 32 + quad * 8);

    // l-sum via ones-MFMA (C layout == oacc rows)
#pragma unroll
    for (int t = 0; t < 2; ++t) {
      lacc[t] = __builtin_amdgcn_mfma_f32_16x16x32_bf16(pa[t][0], ones, lacc[t], 0, 0, 0);
      lacc[t] = __builtin_amdgcn_mfma_f32_16x16x32_bf16(pa[t][1], ones, lacc[t], 0, 0, 0);
    }

    // V B-frags: row = dt*16+l16 (d), chunk hf*4+quad (key/8), swizzled
#pragma unroll
    for (int dt = 0; dt < 4; ++dt) {
      bf16x8_t vf0 = *(const bf16x8_t*)(Vs + (dt * 16 + l16) * 64 + ((quad ^ swz) * 8));
      bf16x8_t vf1 = *(const bf16x8_t*)(Vs + (dt * 16 + l16) * 64 + (((4 | quad) ^ swz) * 8));
#pragma unroll
      for (int t = 0; t < 2; ++t) {
        oacc[t][dt] = __builtin_amdgcn_mfma_f32_16x16x32_bf16(pa[t][0], vf0, oacc[t][dt], 0, 0, 0);
        oacc[t][dt] = __builtin_amdgcn_mfma_f32_16x16x32_bf16(pa[t][1], vf1, oacc[t][dt], 0, 0, 0);
      }
    }
  }

#pragma unroll
  for (int t = 0; t < 2; ++t)
#pragma unroll
    for (int r = 0; r < 4; ++r) {
      float inv = 1.f / lacc[t][r];
      size_t orow = (size_t)(b * 2048 + q0 + t * 16 + quad * 4 + r) * 512 + h * 64;
#pragma unroll
      for (int dt = 0; dt < 4; ++dt)
        O[orow + dt * 16 + l16] = (__bf16)(oacc[t][dt][r] * inv);
    }
}

// ---------------- launch ----------------
extern "C" void kernel_launch(void* const* d_in, const int* in_sizes, int n_in,
                              void* d_out, int out_size, void* d_ws, size_t ws_size,
                              hipStream_t stream) {
  const float* x    = (const float*)d_in[0];
  const float* ctx  = (const float*)d_in[1];
  const float* Wq   = (const float*)d_in[2];
  const float* Wk   = (const float*)d_in[3];
  const float* Wv   = (const float*)d_in[4];
  const float* Wout = (const float*)d_in[5];
  const float* bout = (const float*)d_in[6];
  float* out = (float*)d_out;

  char* ws = (char*)d_ws;
  size_t off = 0;
  auto alloc = [&](size_t bytes) {
    void* p = ws + off;
    off = (off + bytes + 255) & ~(size_t)255;
    return p;
  };
  __bf16* xb    = (__bf16*)alloc((size_t)8192 * 1024 * 2);
  __bf16* cb    = (__bf16*)alloc((size_t)4096 * 768 * 2);
  __bf16* WqT   = (__bf16*)alloc((size_t)512 * 1024 * 2);
  __bf16* WkvT  = (__bf16*)alloc((size_t)1024 * 768 * 2);
  __bf16* WoutT = (__bf16*)alloc((size_t)1024 * 512 * 2);
  __bf16* Qs    = (__bf16*)alloc((size_t)8192 * 512 * 2);
  __bf16* Ks    = (__bf16*)alloc((size_t)4096 * 512 * 2);
  __bf16* Vt    = (__bf16*)alloc((size_t)4 * 512 * 1024 * 2);
  __bf16* Os    = (__bf16*)alloc((size_t)8192 * 512 * 2);

  const float QSCALE = 0.125f * 1.4426950408889634f;  // dh^-0.5 * log2(e)

  prep_cast<<<5632, 256, 0, stream>>>(x, xb, ctx, cb);
  prep_weights<<<1792, 256, 0, stream>>>(Wq, Wk, Wv, Wout, WqT, WkvT, WoutT, QSCALE);
  proj_gemm<<<512, 256, 0, stream>>>(xb, WqT, Qs, cb, WkvT, Ks, Vt);
  attn_kernel<<<dim3(32, 16), 256, 0, stream>>>(Qs, Ks, Vt, Os);
  gemm_out<<<dim3(64, 8), 256, 0, stream>>>(Os, WoutT, out, bout);
}

// Round 7
// 182.491 us; speedup vs baseline: 1.4682x; 1.0140x over previous
//
#include <hip/hip_runtime.h>

// CrossAttention: b=4, n=2048, m=1024, qd=1024, cd=768, heads=8, dh=64, inner=512
// Round 7:
//   prep_all : cast x,ctx -> bf16 AND 4 weight transposes in ONE launch
//   proj_gemm: fused Q + KV projection, 128x128 tiles
//   attn     : 128-key staging iters (two 64-key sub-tiles per barrier pair,
//              halves barrier drains), XOR-swizzled LDS K/V, ones-MFMA l-sum
//   gemm_out : 128x128 f32+bias

typedef __bf16 bf16x8_t __attribute__((ext_vector_type(8)));
typedef __bf16 bf16x4_t __attribute__((ext_vector_type(4)));
typedef float  f32x4_t  __attribute__((ext_vector_type(4)));

#define GLOAD_LDS16(gptr, lptr)                                                  \
  __builtin_amdgcn_global_load_lds(                                              \
      (const __attribute__((address_space(1))) void*)(gptr),                     \
      (__attribute__((address_space(3))) void*)(lptr), 16, 0, 0)

// ---------------- fused prep: casts + weight transposes ----------------
__global__ __launch_bounds__(256) void prep_all(const float* __restrict__ x,
                                                __bf16* __restrict__ xb,
                                                const float* __restrict__ ctx,
                                                __bf16* __restrict__ cb,
                                                const float* __restrict__ Wq,
                                                const float* __restrict__ Wk,
                                                const float* __restrict__ Wv,
                                                const float* __restrict__ Wout,
                                                __bf16* __restrict__ WqT,
                                                __bf16* __restrict__ WkvT,
                                                __bf16* __restrict__ WoutT,
                                                float qscale) {
  __shared__ float tile[32][33];
  const int NCAST = 5632;  // cast blocks: (8192*1024 + 4096*768)/8/256
  int bid = blockIdx.x;
  if (bid < NCAST) {
    const int NX = 8192 * 1024 / 8;
    int g = bid * 256 + threadIdx.x;
    const float* src;
    __bf16* dst;
    if (g < NX) { src = x; dst = xb; }
    else        { src = ctx; dst = cb; g -= NX; }
    size_t i = (size_t)g * 8;
    float4 a = *(const float4*)(src + i);
    float4 b = *(const float4*)(src + i + 4);
    bf16x8_t v;
    v[0] = (__bf16)a.x; v[1] = (__bf16)a.y; v[2] = (__bf16)a.z; v[3] = (__bf16)a.w;
    v[4] = (__bf16)b.x; v[5] = (__bf16)b.y; v[6] = (__bf16)b.z; v[7] = (__bf16)b.w;
    *(bf16x8_t*)(dst + i) = v;
    return;
  }
  bid -= NCAST;
  const float* src; __bf16* dst; int R, C; float scale; int t;
  if (bid < 512)       { src = Wq;   dst = WqT;   R = 1024; C = 512;  scale = qscale; t = bid; }
  else if (bid < 896)  { src = Wk;   dst = WkvT;  R = 768;  C = 512;  scale = 1.f; t = bid - 512; }
  else if (bid < 1280) { src = Wv;   dst = WkvT + (size_t)512 * 768; R = 768; C = 512; scale = 1.f; t = bid - 896; }
  else                 { src = Wout; dst = WoutT; R = 512;  C = 1024; scale = 1.f; t = bid - 1280; }
  int tilesX = C >> 5;
  int c0 = (t % tilesX) * 32, r0 = (t / tilesX) * 32;
  int tx = threadIdx.x & 31, ty = threadIdx.x >> 5;
#pragma unroll
  for (int i = 0; i < 32; i += 8)
    tile[ty + i][tx] = src[(size_t)(r0 + ty + i) * C + (c0 + tx)];
  __syncthreads();
#pragma unroll
  for (int i = 0; i < 32; i += 8)
    dst[(size_t)(c0 + ty + i) * R + (r0 + tx)] = (__bf16)(tile[tx][ty + i] * scale);
}

// ------------- fused Q + KV projection GEMM, 128x128 tiles -------------
__global__ __launch_bounds__(256) void proj_gemm(const __bf16* __restrict__ xb,
                                                 const __bf16* __restrict__ WqT,
                                                 __bf16* __restrict__ Qs,
                                                 const __bf16* __restrict__ cb,
                                                 const __bf16* __restrict__ WkvT,
                                                 __bf16* __restrict__ Ks,
                                                 __bf16* __restrict__ Vt) {
  __shared__ __align__(16) __bf16 As[128 * 32];
  __shared__ __align__(16) __bf16 Bs[128 * 32];
  const int bid = blockIdx.x;
  const bool isQ = bid < 256;
  const int idx = isQ ? bid : bid - 256;
  const __bf16 *A, *B;
  int K, bm, bn;
  if (isQ) { A = xb; B = WqT;  K = 1024; bm = (idx >> 2) * 128; bn = (idx & 3) * 128; }
  else     { A = cb; B = WkvT; K = 768;  bm = (idx >> 3) * 128; bn = (idx & 7) * 128; }

  const int tid  = threadIdx.x;
  const int wave = tid >> 6;
  const int lane = tid & 63;
  const int quad = lane >> 4;
  const int l16  = lane & 15;
  const int wm = (wave >> 1) * 64;
  const int wn = (wave & 1) * 64;
  const int sRow = tid >> 2;
  const int sCol = (tid & 3) * 8;

  f32x4_t acc[4][4] = {};

  for (int kk = 0; kk < K; kk += 32) {
    __syncthreads();
#pragma unroll
    for (int it = 0; it < 2; ++it) {
      GLOAD_LDS16(A + (size_t)(bm + it * 64 + sRow) * K + kk + sCol, As + it * 2048 + wave * 512);
      GLOAD_LDS16(B + (size_t)(bn + it * 64 + sRow) * K + kk + sCol, Bs + it * 2048 + wave * 512);
    }
    __syncthreads();
    bf16x8_t af[4], bf[4];
#pragma unroll
    for (int i = 0; i < 4; ++i) {
      af[i] = *(const bf16x8_t*)(As + (wm + i * 16 + l16) * 32 + quad * 8);
      bf[i] = *(const bf16x8_t*)(Bs + (wn + i * 16 + l16) * 32 + quad * 8);
    }
#pragma unroll
    for (int i = 0; i < 4; ++i)
#pragma unroll
      for (int j = 0; j < 4; ++j)
        acc[i][j] = __builtin_amdgcn_mfma_f32_16x16x32_bf16(af[i], bf[j], acc[i][j], 0, 0, 0);
  }

#pragma unroll
  for (int i = 0; i < 4; ++i) {
    int row = bm + wm + i * 16 + quad * 4;
#pragma unroll
    for (int j = 0; j < 4; ++j) {
      int col = bn + wn + j * 16 + l16;
      f32x4_t v = acc[i][j];
      if (isQ) {
#pragma unroll
        for (int r = 0; r < 4; ++r) Qs[(size_t)(row + r) * 512 + col] = (__bf16)v[r];
      } else if (col < 512) {
#pragma unroll
        for (int r = 0; r < 4; ++r) Ks[(size_t)(row + r) * 512 + col] = (__bf16)v[r];
      } else {
        int dg = col - 512;
        int bb = row >> 10, m0 = row & 1023;
        bf16x4_t pk;
        pk[0] = (__bf16)v[0]; pk[1] = (__bf16)v[1];
        pk[2] = (__bf16)v[2]; pk[3] = (__bf16)v[3];
        *(bf16x4_t*)(Vt + ((size_t)bb * 512 + dg) * 1024 + m0) = pk;
      }
    }
  }
}

// ------------- out projection GEMM, 128x128 tiles, f32 + bias -------------
__global__ __launch_bounds__(256) void gemm_out(const __bf16* __restrict__ A,
                                                const __bf16* __restrict__ B,
                                                float* __restrict__ C,
                                                const float* __restrict__ bias) {
  __shared__ __align__(16) __bf16 As[128 * 32];
  __shared__ __align__(16) __bf16 Bs[128 * 32];
  const int K = 512, N = 1024;
  const int tid  = threadIdx.x;
  const int wave = tid >> 6;
  const int lane = tid & 63;
  const int quad = lane >> 4;
  const int l16  = lane & 15;
  const int wm = (wave >> 1) * 64;
  const int wn = (wave & 1) * 64;
  const int bm = blockIdx.x * 128;
  const int bn = blockIdx.y * 128;
  const int sRow = tid >> 2;
  const int sCol = (tid & 3) * 8;

  f32x4_t acc[4][4] = {};

  for (int kk = 0; kk < K; kk += 32) {
    __syncthreads();
#pragma unroll
    for (int it = 0; it < 2; ++it) {
      GLOAD_LDS16(A + (size_t)(bm + it * 64 + sRow) * K + kk + sCol, As + it * 2048 + wave * 512);
      GLOAD_LDS16(B + (size_t)(bn + it * 64 + sRow) * K + kk + sCol, Bs + it * 2048 + wave * 512);
    }
    __syncthreads();
    bf16x8_t af[4], bf[4];
#pragma unroll
    for (int i = 0; i < 4; ++i) {
      af[i] = *(const bf16x8_t*)(As + (wm + i * 16 + l16) * 32 + quad * 8);
      bf[i] = *(const bf16x8_t*)(Bs + (wn + i * 16 + l16) * 32 + quad * 8);
    }
#pragma unroll
    for (int i = 0; i < 4; ++i)
#pragma unroll
      for (int j = 0; j < 4; ++j)
        acc[i][j] = __builtin_amdgcn_mfma_f32_16x16x32_bf16(af[i], bf[j], acc[i][j], 0, 0, 0);
  }

#pragma unroll
  for (int i = 0; i < 4; ++i) {
    int row = bm + wm + i * 16 + quad * 4;
#pragma unroll
    for (int j = 0; j < 4; ++j) {
      int col = bn + wn + j * 16 + l16;
      float bb = bias[col];
      f32x4_t v = acc[i][j];
#pragma unroll
      for (int r = 0; r < 4; ++r) C[(size_t)(row + r) * N + col] = v[r] + bb;
    }
  }
}

// ------------- flash attention: 128-key iters, two swizzled 64-key sub-tiles -------------
// grid (32 hb, 16 qt) = 512 blocks, 4 waves, 32 q/wave (128 q/block).
// Per iter: one barrier pair stages K[2][64][64] + V[2][64][64] (32 KB), then
// two 64-key compute halves (72 MFMA per barrier pair vs 36 in round 6).
__global__ __launch_bounds__(256) void attn_kernel(const __bf16* __restrict__ Q,
                                                   const __bf16* __restrict__ K,
                                                   const __bf16* __restrict__ Vt,
                                                   __bf16* __restrict__ O) {
  const int hb = blockIdx.x, h = hb >> 2, b = hb & 3;
  const int qt = blockIdx.y;
  const int tid = threadIdx.x, wave = tid >> 6, lane = tid & 63;
  const int quad = lane >> 4, l16 = lane & 15;

  __shared__ __align__(16) __bf16 Kt[2][64 * 64];
  __shared__ __align__(16) __bf16 Vs[2][64 * 64];
  __shared__ __align__(16) __bf16 Ps[4][32 * 72];
  __bf16* myP = Ps[wave];

  const int q0 = qt * 128 + wave * 32;

  bf16x8_t qa[2][2];
#pragma unroll
  for (int t = 0; t < 2; ++t)
#pragma unroll
    for (int hf = 0; hf < 2; ++hf)
      qa[t][hf] = *(const bf16x8_t*)(Q + (size_t)(b * 2048 + q0 + t * 16 + l16) * 512 +
                                     h * 64 + hf * 32 + quad * 8);

  const __bf16* Kb = K + (size_t)b * 1024 * 512 + h * 64;
  const __bf16* Vb = Vt + (size_t)b * 512 * 1024 + (size_t)h * 64 * 1024;

  bf16x8_t ones;
#pragma unroll
  for (int j = 0; j < 8; ++j) ones[j] = (__bf16)1.0f;

  f32x4_t oacc[2][4] = {};
  f32x4_t lacc[2] = {};

  // staging: lane -> 16B slot; local row = base + lane/8, slot p = lane%8
  // holds global chunk c = p ^ (lane>>3) (row&7 == lane>>3 since base%8==0).
  const int sr = lane >> 3;
  const int sc = (lane & 7) ^ sr;
  const int swz = l16 & 7;

  for (int mm = 0; mm < 1024; mm += 128) {
    __syncthreads();
#pragma unroll
    for (int s = 0; s < 2; ++s)
#pragma unroll
      for (int t = 0; t < 2; ++t) {
        const int rl = wave * 16 + t * 8;
        GLOAD_LDS16(Kb + (size_t)(mm + s * 64 + rl + sr) * 512 + sc * 8, Kt[s] + rl * 64);
        GLOAD_LDS16(Vb + (size_t)(rl + sr) * 1024 + mm + s * 64 + sc * 8, Vs[s] + rl * 64);
      }
    __syncthreads();

#pragma unroll
    for (int half = 0; half < 2; ++half) {
      // K B-frags
      bf16x8_t kf[4][2];
#pragma unroll
      for (int nt = 0; nt < 4; ++nt)
#pragma unroll
        for (int hf = 0; hf < 2; ++hf)
          kf[nt][hf] = *(const bf16x8_t*)(Kt[half] + (nt * 16 + l16) * 64 +
                                          (((hf << 2) | quad) ^ swz) * 8);

      // S = Q K^T
      f32x4_t s[2][4];
#pragma unroll
      for (int t = 0; t < 2; ++t)
#pragma unroll
        for (int nt = 0; nt < 4; ++nt) {
          f32x4_t z = {};
          z = __builtin_amdgcn_mfma_f32_16x16x32_bf16(qa[t][0], kf[nt][0], z, 0, 0, 0);
          s[t][nt] = __builtin_amdgcn_mfma_f32_16x16x32_bf16(qa[t][1], kf[nt][1], z, 0, 0, 0);
        }

      // p = exp2(s) -> per-wave LDS (A-layout rows)
#pragma unroll
      for (int t = 0; t < 2; ++t)
#pragma unroll
        for (int nt = 0; nt < 4; ++nt)
#pragma unroll
          for (int r = 0; r < 4; ++r)
            myP[(t * 16 + quad * 4 + r) * 72 + nt * 16 + l16] =
                (__bf16)__builtin_exp2f(s[t][nt][r]);

      bf16x8_t pa[2][2];
#pragma unroll
      for (int t = 0; t < 2; ++t)
#pragma unroll
        for (int hf = 0; hf < 2; ++hf)
          pa[t][hf] = *(const bf16x8_t*)(myP + (t * 16 + l16) * 72 + hf * 32 + quad * 8);

      // l-sum via ones-MFMA
#pragma unroll
      for (int t = 0; t < 2; ++t) {
        lacc[t] = __builtin_amdgcn_mfma_f32_16x16x32_bf16(pa[t][0], ones, lacc[t], 0, 0, 0);
        lacc[t] = __builtin_amdgcn_mfma_f32_16x16x32_bf16(pa[t][1], ones, lacc[t], 0, 0, 0);
      }

      // O += P V
#pragma unroll
      for (int dt = 0; dt < 4; ++dt) {
        bf16x8_t vf0 = *(const bf16x8_t*)(Vs[half] + (dt * 16 + l16) * 64 + ((quad ^ swz) * 8));
        bf16x8_t vf1 = *(const bf16x8_t*)(Vs[half] + (dt * 16 + l16) * 64 + (((4 | quad) ^ swz) * 8));
#pragma unroll
        for (int t = 0; t < 2; ++t) {
          oacc[t][dt] = __builtin_amdgcn_mfma_f32_16x16x32_bf16(pa[t][0], vf0, oacc[t][dt], 0, 0, 0);
          oacc[t][dt] = __builtin_amdgcn_mfma_f32_16x16x32_bf16(pa[t][1], vf1, oacc[t][dt], 0, 0, 0);
        }
      }
    }
  }

#pragma unroll
  for (int t = 0; t < 2; ++t)
#pragma unroll
    for (int r = 0; r < 4; ++r) {
      float inv = 1.f / lacc[t][r];
      size_t orow = (size_t)(b * 2048 + q0 + t * 16 + quad * 4 + r) * 512 + h * 64;
#pragma unroll
      for (int dt = 0; dt < 4; ++dt)
        O[orow + dt * 16 + l16] = (__bf16)(oacc[t][dt][r] * inv);
    }
}

// ---------------- launch ----------------
extern "C" void kernel_launch(void* const* d_in, const int* in_sizes, int n_in,
                              void* d_out, int out_size, void* d_ws, size_t ws_size,
                              hipStream_t stream) {
  const float* x    = (const float*)d_in[0];
  const float* ctx  = (const float*)d_in[1];
  const float* Wq   = (const float*)d_in[2];
  const float* Wk   = (const float*)d_in[3];
  const float* Wv   = (const float*)d_in[4];
  const float* Wout = (const float*)d_in[5];
  const float* bout = (const float*)d_in[6];
  float* out = (float*)d_out;

  char* ws = (char*)d_ws;
  size_t off = 0;
  auto alloc = [&](size_t bytes) {
    void* p = ws + off;
    off = (off + bytes + 255) & ~(size_t)255;
    return p;
  };
  __bf16* xb    = (__bf16*)alloc((size_t)8192 * 1024 * 2);
  __bf16* cb    = (__bf16*)alloc((size_t)4096 * 768 * 2);
  __bf16* WqT   = (__bf16*)alloc((size_t)512 * 1024 * 2);
  __bf16* WkvT  = (__bf16*)alloc((size_t)1024 * 768 * 2);
  __bf16* WoutT = (__bf16*)alloc((size_t)1024 * 512 * 2);
  __bf16* Qs    = (__bf16*)alloc((size_t)8192 * 512 * 2);
  __bf16* Ks    = (__bf16*)alloc((size_t)4096 * 512 * 2);
  __bf16* Vt    = (__bf16*)alloc((size_t)4 * 512 * 1024 * 2);
  __bf16* Os    = (__bf16*)alloc((size_t)8192 * 512 * 2);

  const float QSCALE = 0.125f * 1.4426950408889634f;  // dh^-0.5 * log2(e)

  prep_all<<<5632 + 1792, 256, 0, stream>>>(x, xb, ctx, cb, Wq, Wk, Wv, Wout,
                                            WqT, WkvT, WoutT, QSCALE);
  proj_gemm<<<512, 256, 0, stream>>>(xb, WqT, Qs, cb, WkvT, Ks, Vt);
  attn_kernel<<<dim3(32, 16), 256, 0, stream>>>(Qs, Ks, Vt, Os);
  gemm_out<<<dim3(64, 8), 256, 0, stream>>>(Os, WoutT, out, bout);
}